// Round 2
// baseline (1839.305 us; speedup 1.0000x reference)
//
#include <hip/hip_runtime.h>
#include <hip/hip_bf16.h>
#include <math.h>

// Problem constants (from setup_inputs): B=4, Cin=48, Cout=64, H=368, W=640
#define B_  4
#define H_  368
#define W_  640
#define HW_ (H_ * W_)

// ---------------------------------------------------------------------------
// Direct 3x3 SAME conv + bias + relu.  CIN=48 fixed, COUT templated (48 / 64).
// Block: 256 threads -> 16x16 output tile, all COUT channels.
// Thread: 4 consecutive-j pixels x (COUT/4) output channels.
//   tid = og*64 + slot ; og = cout group (0..3), slot -> (row 0..15, cg4 0..3)
// LDS: x chunk [8][18][19] (pad col -> odd stride, <=2-way conflicts = free),
//      w chunk [72][COUT+4]  (reads are wave-uniform broadcasts).
// ---------------------------------------------------------------------------
template<int COUT>
__global__ __launch_bounds__(256, 4)
void conv3x3_relu_k(const float* __restrict__ in, const float* __restrict__ wgt,
                    const float* __restrict__ bias, float* __restrict__ out)
{
    constexpr int CIN   = 48;
    constexpr int CHUNK = 8;
    constexpr int CPT   = COUT / 4;   // couts per thread (12 or 16)
    constexpr int WPAD  = COUT + 4;   // rows 16B-aligned

    __shared__ float xs[CHUNK][18][19];
    __shared__ float ws[CHUNK * 9][WPAD];

    const int tid  = threadIdx.x;
    const int og   = tid >> 6;        // 0..3
    const int slot = tid & 63;
    const int row  = slot >> 2;       // 0..15
    const int cg4  = slot & 3;        // 0..3
    const int o0   = og * CPT;

    const int tj = blockIdx.x * 16;
    const int ti = blockIdx.y * 16;
    const int b  = blockIdx.z;

    float acc[CPT][4];
    #pragma unroll
    for (int n = 0; n < CPT; ++n) {
        float bv = bias[o0 + n];
        acc[n][0] = bv; acc[n][1] = bv; acc[n][2] = bv; acc[n][3] = bv;
    }

    for (int c0 = 0; c0 < CIN; c0 += CHUNK) {
        __syncthreads();   // protect LDS from previous iteration's readers

        // ---- stage input chunk (zero-padded halo) ----
        for (int idx = tid; idx < CHUNK * 18 * 18; idx += 256) {
            int cc  = idx / 324;
            int rem = idx - cc * 324;
            int r   = rem / 18;
            int c   = rem - r * 18;
            int gi  = ti - 1 + r;
            int gj  = tj - 1 + c;
            float v = 0.f;
            if ((unsigned)gi < (unsigned)H_ && (unsigned)gj < (unsigned)W_)
                v = in[(((size_t)b * CIN + c0 + cc) * H_ + gi) * W_ + gj];
            xs[cc][r][c] = v;
        }
        // ---- stage weight chunk: ws[cc*9+k][o] = wgt[o][c0+cc][k] ----
        for (int idx = tid; idx < COUT * CHUNK * 9; idx += 256) {
            int o   = idx / (CHUNK * 9);
            int rem = idx - o * (CHUNK * 9);      // cc*9 + k
            ws[rem][o] = wgt[((size_t)o * CIN + c0) * 9 + rem];
        }
        __syncthreads();

        #pragma unroll 1
        for (int cc = 0; cc < CHUNK; ++cc) {
            #pragma unroll
            for (int k = 0; k < 9; ++k) {
                const int di = k / 3, dj = k % 3;
                float xv[4];
                #pragma unroll
                for (int p = 0; p < 4; ++p)
                    xv[p] = xs[cc][row + di][cg4 * 4 + dj + p];
                const float4* wp =
                    reinterpret_cast<const float4*>(&ws[cc * 9 + k][o0]);
                #pragma unroll
                for (int q = 0; q < CPT / 4; ++q) {
                    float4 wv = wp[q];
                    #pragma unroll
                    for (int p = 0; p < 4; ++p) {
                        acc[q * 4 + 0][p] += wv.x * xv[p];
                        acc[q * 4 + 1][p] += wv.y * xv[p];
                        acc[q * 4 + 2][p] += wv.z * xv[p];
                        acc[q * 4 + 3][p] += wv.w * xv[p];
                    }
                }
            }
        }
    }

    // ---- store (relu), float4 along j ----
    const int oi = ti + row;
    const int oj = tj + cg4 * 4;
    #pragma unroll
    for (int n = 0; n < CPT; ++n) {
        float4 v;
        v.x = fmaxf(acc[n][0], 0.f);
        v.y = fmaxf(acc[n][1], 0.f);
        v.z = fmaxf(acc[n][2], 0.f);
        v.w = fmaxf(acc[n][3], 0.f);
        *reinterpret_cast<float4*>(
            &out[(((size_t)b * COUT + o0 + n) * H_ + oi) * W_ + oj]) = v;
    }
}

// ---------------------------------------------------------------------------
// Fused epilogue: per-pixel channel-MLP (64->128 relu ->10), softmax(9),
// sigmoid(1), nearest warp of prev_filtered, 3x3 per-pixel filter of radiance,
// temporal blend.  One thread per pixel.
// ---------------------------------------------------------------------------
__global__ __launch_bounds__(256, 4)
void epilogue_k(const float* __restrict__ conv, const float* __restrict__ rad,
                const float* __restrict__ prev, const float* __restrict__ mv,
                const float* __restrict__ mw1, const float* __restrict__ mb1,
                const float* __restrict__ mw2, const float* __restrict__ mb2,
                float* __restrict__ filtered)
{
    constexpr int CC = 64, DD = 128;
    __shared__ float w1s[DD][CC];   // 32 KB
    __shared__ float w2s[10][DD];   // 5 KB
    __shared__ float b1s[DD];
    __shared__ float b2s[16];

    const int tid = threadIdx.x;
    for (int idx = tid; idx < DD * CC; idx += 256)
        (&w1s[0][0])[idx] = mw1[idx];
    for (int idx = tid; idx < 10 * DD; idx += 256)
        (&w2s[0][0])[idx] = mw2[idx];
    if (tid < DD) b1s[tid] = mb1[tid];
    if (tid < 10) b2s[tid] = mb2[tid];
    __syncthreads();

    const int p   = blockIdx.x * 256 + tid;       // 0 .. B*H*W-1 (exact grid)
    const int b   = p / HW_;
    const int rem = p - b * HW_;
    const int i   = rem / W_;
    const int j   = rem - i * W_;

    // conv channels for this pixel (coalesced across lanes per channel)
    float x[CC];
    const float* cp = conv + (size_t)b * 64 * HW_ + rem;
    #pragma unroll
    for (int c = 0; c < CC; ++c) x[c] = cp[(size_t)c * HW_];

    float o[10];
    #pragma unroll
    for (int q = 0; q < 10; ++q) o[q] = b2s[q];

    #pragma unroll 2
    for (int d = 0; d < DD; ++d) {
        float a = b1s[d];
        const float4* wrow = reinterpret_cast<const float4*>(&w1s[d][0]);
        #pragma unroll
        for (int c4 = 0; c4 < CC / 4; ++c4) {
            float4 wv = wrow[c4];
            a += wv.x * x[c4 * 4 + 0] + wv.y * x[c4 * 4 + 1]
               + wv.z * x[c4 * 4 + 2] + wv.w * x[c4 * 4 + 3];
        }
        float h = fmaxf(a, 0.f);
        #pragma unroll
        for (int q = 0; q < 10; ++q) o[q] += w2s[q][d] * h;
    }

    // softmax over o[0..8]
    float m = o[0];
    #pragma unroll
    for (int q = 1; q < 9; ++q) m = fmaxf(m, o[q]);
    float kern[9];
    float s = 0.f;
    #pragma unroll
    for (int q = 0; q < 9; ++q) { kern[q] = expf(o[q] - m); s += kern[q]; }
    const float inv_s = 1.f / s;
    #pragma unroll
    for (int q = 0; q < 9; ++q) kern[q] *= inv_s;

    // temporal alpha
    const float ta = 1.f / (1.f + expf(-o[9]));
    const float om = 1.f - ta;

    // nearest warp coords: clip(i + mv[:,1]) / clip(j + mv[:,0]) then trunc
    const float mv0 = mv[((size_t)b * 2 + 0) * HW_ + rem];
    const float mv1 = mv[((size_t)b * 2 + 1) * HW_ + rem];
    float fi = fminf(fmaxf((float)i + mv1, 0.f), (float)(H_ - 1));
    float fj = fminf(fmaxf((float)j + mv0, 0.f), (float)(W_ - 1));
    const int wi = (int)fi;
    const int wj = (int)fj;

    // hoisted 3x3 neighborhood validity/offsets (shared across the 3 channels)
    int noff[9];
    float nmask[9];
    #pragma unroll
    for (int k = 0; k < 9; ++k) {
        int ii = i + k / 3 - 1;
        int jj = j + k % 3 - 1;
        bool ok = ((unsigned)ii < (unsigned)H_) && ((unsigned)jj < (unsigned)W_);
        noff[k]  = ok ? (ii * W_ + jj) : 0;
        nmask[k] = ok ? 1.f : 0.f;
    }

    #pragma unroll
    for (int c = 0; c < 3; ++c) {
        const float* rc = rad + ((size_t)b * 3 + c) * HW_;
        float acc = 0.f;
        #pragma unroll
        for (int k = 0; k < 9; ++k)
            acc += kern[k] * nmask[k] * rc[noff[k]];
        const float pv = prev[(((size_t)b * 3 + c) * H_ + wi) * W_ + wj];
        filtered[((size_t)b * 3 + c) * HW_ + rem] = acc * om + pv * ta;
    }
}

// ---------------------------------------------------------------------------
extern "C" void kernel_launch(void* const* d_in, const int* in_sizes, int n_in,
                              void* d_out, int out_size, void* d_ws, size_t ws_size,
                              hipStream_t stream)
{
    const float* input    = (const float*)d_in[0];
    const float* radiance = (const float*)d_in[1];
    const float* prev     = (const float*)d_in[2];
    const float* motion   = (const float*)d_in[3];
    const float* w1       = (const float*)d_in[4];
    const float* b1       = (const float*)d_in[5];
    const float* w2       = (const float*)d_in[6];
    const float* b2       = (const float*)d_in[7];
    const float* mw1      = (const float*)d_in[8];
    const float* mb1      = (const float*)d_in[9];
    const float* mw2      = (const float*)d_in[10];
    const float* mb2      = (const float*)d_in[11];

    float* conv_out = (float*)d_out;                       // (4,64,368,640)
    float* filtered = conv_out + (size_t)B_ * 64 * HW_;    // (4,3,368,640)
    float* h_buf    = (float*)d_ws;                        // (4,48,368,640) = 181 MB

    dim3 blk(256);
    dim3 grid(W_ / 16, H_ / 16, B_);   // 40 x 23 x 4 — exact tiling

    conv3x3_relu_k<48><<<grid, blk, 0, stream>>>(input, w1, b1, h_buf);
    conv3x3_relu_k<64><<<grid, blk, 0, stream>>>(h_buf, w2, b2, conv_out);

    epilogue_k<<<dim3((B_ * HW_) / 256), blk, 0, stream>>>(
        conv_out, radiance, prev, motion, mw1, mb1, mw2, mb2, filtered);
}